// Round 7
// baseline (813.671 us; speedup 1.0000x reference)
//
#include <hip/hip_runtime.h>
#include <hip/hip_bf16.h>

#define NG 72

typedef float f32x4 __attribute__((ext_vector_type(4)));
typedef short s16x8 __attribute__((ext_vector_type(8)));

__device__ __forceinline__ short f2bf(float f) {
  return (short)__builtin_bit_cast(unsigned short, __float2bfloat16(f));
}

// ---------------- conv1 via MFMA implicit-GEMM ----------------
// (64,216,46,46) -> k5 g72 (3->8) -> relu -> pool2 -> (64,576,21,21)
// Per (b,g): D[16(oc, 8 used)][n] = W'[16][128] x B[128][n], k' = (ic*5+ky)*8+kx
// (kx 5..7 zero-weight). B-frag = one aligned ds_read_b128. N-tile = 84 =
// 2 pre-pool rows = 1 pooled row; pool via LDS buffer.
__global__ __launch_bounds__(256) void conv1_k(const float* __restrict__ x,
                                               const float* __restrict__ w,
                                               const float* __restrict__ bias,
                                               float* __restrict__ out) {
  const int b = blockIdx.x / NG, g = blockIdx.x % NG;
  __shared__ float sx[3 * 46 * 48 + 16];   // fp32 input, pitch 48, zeroed pads
  __shared__ s16x8 sB8[96 * 17];           // im2col bf16 [n][17 chunks] (15 real+pad)
  __shared__ float spool[8 * 100];         // pre-pool conv [oc][n<96], pitch 100
  __shared__ float sb[8];

  // zero whole B panel once: pad rows (n>=84) and chunk 15 stay 0 forever
  {
    const s16x8 z = {0, 0, 0, 0, 0, 0, 0, 0};
    for (int i = threadIdx.x; i < 96 * 17; i += 256) sB8[i] = z;
  }
  // stage x as fp32
  const float* xp = x + (size_t)(b * 216 + g * 3) * 2116;
  const float4* xp4 = (const float4*)xp;   // 3*2116 = 6348 = 1587 float4
  for (int i = threadIdx.x; i < 1587; i += 256) {
    const float4 v = xp4[i];
#pragma unroll
    for (int j = 0; j < 4; j++) {
      const int k = 4 * i + j;
      const int ic = k / 2116, rem = k % 2116, r = rem / 46, c = rem % 46;
      sx[(ic * 46 + r) * 48 + c] = (&v.x)[j];
    }
  }
  // zero pad cols 46,47 of each row + 16-float tail (build over-reads hit these)
  for (int i = threadIdx.x; i < 3 * 46 * 2 + 16; i += 256) {
    if (i < 276) sx[(i >> 1) * 48 + 46 + (i & 1)] = 0.f;
    else         sx[3 * 46 * 48 + (i - 276)] = 0.f;
  }
  if (threadIdx.x < 8) sb[threadIdx.x] = bias[g * 8 + threadIdx.x];

  // A fragments (weights) in registers: lane holds A[oc=lane&15][k'=kc*32+hi*8+i]
  const int lane = threadIdx.x & 63;
  const int cidx = lane & 15, hi = lane >> 4;   // cidx = oc for A, col n for B/D
  s16x8 afrag[4];
#pragma unroll
  for (int kc = 0; kc < 4; kc++) {
    s16x8 a = {0, 0, 0, 0, 0, 0, 0, 0};
    const int row15 = kc * 4 + hi;              // (ic,ky) index
    if (cidx < 8 && row15 < 15) {
      const int ic = row15 / 5, ky = row15 % 5;
      const float* wp = w + (size_t)((g * 8 + cidx) * 3 + ic) * 25 + ky * 5;
#pragma unroll
      for (int kx = 0; kx < 5; kx++) a[kx] = f2bf(wp[kx]);
    }
    afrag[kc] = a;
  }
  __syncthreads();

  const int wid = threadIdx.x >> 6;
  for (int t = 0; t < 21; t++) {
    // build B: 84 n-rows x 15 (ic,ky)-chunks; each chunk = 8 contiguous floats
    for (int c = threadIdx.x; c < 84 * 15; c += 256) {
      const int n = c / 15, row15 = c % 15;
      const int ic = row15 / 5, ky = row15 % 5;
      const int yl = (n >= 42) ? 1 : 0, xx = n - 42 * yl;
      const float* src = &sx[(ic * 46 + 2 * t + yl + ky) * 48 + xx];
      s16x8 v;
#pragma unroll
      for (int j = 0; j < 8; j++) v[j] = f2bf(src[j]);
      sB8[n * 17 + row15] = v;
    }
    __syncthreads();
    // mfma: 6 N-subtiles of 16; wave w takes subtiles {w, w+4}
#pragma unroll 1
    for (int si = 0; si < 2; si++) {
      const int s = wid + 4 * si;
      if (s < 6) {
        const int n = s * 16 + cidx;
        f32x4 acc = {0.f, 0.f, 0.f, 0.f};
#pragma unroll
        for (int kc = 0; kc < 4; kc++) {
          const s16x8 bfrag = sB8[n * 17 + kc * 4 + hi];
          acc = __builtin_amdgcn_mfma_f32_16x16x32_bf16(afrag[kc], bfrag, acc, 0, 0, 0);
        }
        if (hi < 2) {                    // D rows hi*4+r = oc 0..7
#pragma unroll
          for (int r = 0; r < 4; r++) spool[(hi * 4 + r) * 100 + n] = acc[r];
        }
      }
    }
    __syncthreads();
    // pool 2x2 + bias + relu + store one pooled row
    if (threadIdx.x < 168) {
      const int oc = threadIdx.x / 21, xo = threadIdx.x % 21;
      const float* pr = &spool[oc * 100];
      const float v = fmaxf(fmaxf(pr[2 * xo], pr[2 * xo + 1]),
                            fmaxf(pr[42 + 2 * xo], pr[42 + 2 * xo + 1])) + sb[oc];
      out[(size_t)(b * 576 + g * 8 + oc) * 441 + t * 21 + xo] = fmaxf(v, 0.f);
    }
    // no barrier needed here: next build writes sB only; spool next written
    // by mfma(t+1) which is after the post-build barrier
  }
}

// ---------------- conv2: (64,576,21,21) -> k3 (8->16) -> relu -> pool2 -> (64,1152,9,9)
#define C2_NBB 3
__global__ __launch_bounds__(256) void conv2_k(const float* __restrict__ x,
                                               const float* __restrict__ w,
                                               const float* __restrict__ bias,
                                               float* __restrict__ out) {
  const int g = blockIdx.x % NG, b0 = (blockIdx.x / NG) * C2_NBB;
  const int nbb = min(C2_NBB, 64 - b0);
  __shared__ float sx[C2_NBB][8][21][22];
  __shared__ float sw[16 * 8 * 12];     // [oc][ic][12] (9 used), float4-aligned
  __shared__ float sb[16];
  for (int bb = 0; bb < nbb; bb++) {
    const float* xp = x + (size_t)((b0 + bb) * 576 + g * 8) * 441;
    for (int i = threadIdx.x; i < 8 * 441; i += 256) {
      const int ic = i / 441, rem = i % 441, r = rem / 21, c = rem % 21;
      sx[bb][ic][r][c] = xp[i];
    }
  }
  const float* wp = w + (size_t)(g * 16) * 72;
  for (int i = threadIdx.x; i < 16 * 72; i += 256) {
    const int oc = i / 72, rem = i % 72, ic = rem / 9, k = rem % 9;
    sw[(oc * 8 + ic) * 12 + k] = wp[i];
  }
  if (threadIdx.x < 16) sb[threadIdx.x] = bias[g * 16 + threadIdx.x];
  __syncthreads();
  for (int u = threadIdx.x; u < nbb * 81; u += 256) {
    const int bb = u / 81, p = u % 81, py = p / 9, px = p % 9;
    const int iy = 2 * py, ix = 2 * px;
#pragma unroll 1   // sequential halves
    for (int half = 0; half < 2; half++) {
      float acc[8][4];
#pragma unroll
      for (int o = 0; o < 8; o++)
#pragma unroll
        for (int q = 0; q < 4; q++) acc[o][q] = 0.f;
#pragma unroll
      for (int ic = 0; ic < 8; ic++) {
        float win[4][4];
#pragma unroll
        for (int r = 0; r < 4; r++) {
          const float2 a = *(const float2*)&sx[bb][ic][iy + r][ix];
          const float2 c2 = *(const float2*)&sx[bb][ic][iy + r][ix + 2];
          win[r][0] = a.x; win[r][1] = a.y; win[r][2] = c2.x; win[r][3] = c2.y;
        }
#pragma unroll
        for (int o8 = 0; o8 < 8; o8++) {
          const int oc = half * 8 + o8;
          const float4 wA = *(const float4*)&sw[(oc * 8 + ic) * 12];
          const float4 wB = *(const float4*)&sw[(oc * 8 + ic) * 12 + 4];
          const float  w8 = sw[(oc * 8 + ic) * 12 + 8];
          const float wv[9] = {wA.x, wA.y, wA.z, wA.w, wB.x, wB.y, wB.z, wB.w, w8};
#pragma unroll
          for (int ky = 0; ky < 3; ky++)
#pragma unroll
            for (int kx = 0; kx < 3; kx++) {
              const float wv_ = wv[ky * 3 + kx];
              acc[o8][0] = fmaf(win[ky][kx],         wv_, acc[o8][0]);
              acc[o8][1] = fmaf(win[ky][kx + 1],     wv_, acc[o8][1]);
              acc[o8][2] = fmaf(win[ky + 1][kx],     wv_, acc[o8][2]);
              acc[o8][3] = fmaf(win[ky + 1][kx + 1], wv_, acc[o8][3]);
            }
        }
      }
#pragma unroll
      for (int o8 = 0; o8 < 8; o8++) {
        const int oc = half * 8 + o8;
        const float v = fmaxf(fmaxf(acc[o8][0], acc[o8][1]), fmaxf(acc[o8][2], acc[o8][3])) + sb[oc];
        out[(size_t)((b0 + bb) * 1152 + g * 16 + oc) * 81 + p] = fmaxf(v, 0.f);
      }
    }
  }
}

// ---------------- conv3: (64,1152,9,9) -> k3 (16->32) -> relu -> pool2 -> (64,2304,3,3)
#define C3_NBB 7
__global__ __launch_bounds__(256) void conv3_k(const float* __restrict__ x,
                                               const float* __restrict__ w,
                                               const float* __restrict__ bias,
                                               float* __restrict__ out) {
  const int g = blockIdx.x % NG, b0 = (blockIdx.x / NG) * C3_NBB;
  const int nbb = min(C3_NBB, 64 - b0);
  __shared__ float sx[C3_NBB][16 * 90 + 2];
  __shared__ float sw[32 * 16 * 12];
  __shared__ float sb[32];
  for (int bb = 0; bb < nbb; bb++) {
    const float* xp = x + (size_t)((b0 + bb) * 1152 + g * 16) * 81;
    for (int i = threadIdx.x; i < 16 * 81; i += 256) {
      const int ic = i / 81, rem = i % 81, r = rem / 9, c = rem % 9;
      sx[bb][ic * 90 + r * 10 + c] = xp[i];
    }
  }
  const float* wp = w + (size_t)(g * 32) * 144;
  for (int i = threadIdx.x; i < 32 * 144; i += 256) {
    const int oc = i / 144, rem = i % 144, ic = rem / 9, k = rem % 9;
    sw[(oc * 16 + ic) * 12 + k] = wp[i];
  }
  if (threadIdx.x < 32) sb[threadIdx.x] = bias[g * 32 + threadIdx.x];
  __syncthreads();
  const int ocg = threadIdx.x >> 6;          // wave-uniform oc group
  const int lane = threadIdx.x & 63;
  const int bb = lane / 9, p = lane % 9;
  if (bb < nbb) {
    const int py = p / 3, px = p % 3, iy = 2 * py, ix = 2 * px;
    const float* sxb = &sx[bb][0];
    float acc[8][4];
#pragma unroll
    for (int o = 0; o < 8; o++)
#pragma unroll
      for (int q = 0; q < 4; q++) acc[o][q] = 0.f;
#pragma unroll
    for (int ic = 0; ic < 16; ic++) {
      float win[4][4];
#pragma unroll
      for (int r = 0; r < 4; r++) {
        const float2 a = *(const float2*)&sxb[ic * 90 + (iy + r) * 10 + ix];
        const float2 c2 = *(const float2*)&sxb[ic * 90 + (iy + r) * 10 + ix + 2];
        win[r][0] = a.x; win[r][1] = a.y; win[r][2] = c2.x; win[r][3] = c2.y;
      }
#pragma unroll
      for (int o8 = 0; o8 < 8; o8++) {
        const int oc = ocg * 8 + o8;         // wave-uniform -> broadcast reads
        const float4 wA = *(const float4*)&sw[(oc * 16 + ic) * 12];
        const float4 wB = *(const float4*)&sw[(oc * 16 + ic) * 12 + 4];
        const float  w8 = sw[(oc * 16 + ic) * 12 + 8];
        const float wv[9] = {wA.x, wA.y, wA.z, wA.w, wB.x, wB.y, wB.z, wB.w, w8};
#pragma unroll
        for (int ky = 0; ky < 3; ky++)
#pragma unroll
          for (int kx = 0; kx < 3; kx++) {
            const float wv_ = wv[ky * 3 + kx];
            acc[o8][0] = fmaf(win[ky][kx],         wv_, acc[o8][0]);
            acc[o8][1] = fmaf(win[ky][kx + 1],     wv_, acc[o8][1]);
            acc[o8][2] = fmaf(win[ky + 1][kx],     wv_, acc[o8][2]);
            acc[o8][3] = fmaf(win[ky + 1][kx + 1], wv_, acc[o8][3]);
          }
      }
    }
#pragma unroll
    for (int o8 = 0; o8 < 8; o8++) {
      const int oc = ocg * 8 + o8;
      const float v = fmaxf(fmaxf(acc[o8][0], acc[o8][1]), fmaxf(acc[o8][2], acc[o8][3])) + sb[oc];
      out[(size_t)((b0 + bb) * 2304 + g * 32 + oc) * 9 + p] = fmaxf(v, 0.f);
    }
  }
}

// ---------------- fused block-diagonal linear1 (288->64) + linear2 (64->2) + bias
__global__ __launch_bounds__(256) void lin_k(const float* __restrict__ h,
                                             const float* __restrict__ w1,
                                             const float* __restrict__ w2,
                                             const float* __restrict__ b2,
                                             float* __restrict__ out) {
  const int g = blockIdx.x % NG, b0 = (blockIdx.x / NG) * 32;
  __shared__ float sw1[64 * 292];
  __shared__ float sf[32 * 300];
  __shared__ float so[32 * 65];
  __shared__ float sw2[2 * 64];
  __shared__ float sb2[2];
  for (int i = threadIdx.x; i < 64 * 288; i += 256) {
    const int o = i / 288, k = i % 288;
    sw1[o * 292 + k] = w1[(size_t)(g * 64 + o) * 20736 + g * 288 + k];
  }
  for (int i = threadIdx.x; i < 32 * 288; i += 256) {
    const int bb = i / 288, k = i % 288;
    sf[bb * 300 + k] = h[(size_t)(b0 + bb) * 20736 + g * 288 + k];
  }
  if (threadIdx.x < 128) {
    const int j = threadIdx.x >> 6, o = threadIdx.x & 63;
    sw2[j * 64 + o] = w2[(size_t)(g * 2 + j) * 4608 + g * 64 + o];
  }
  if (threadIdx.x < 2) sb2[threadIdx.x] = b2[g * 2 + threadIdx.x];
  __syncthreads();
  const int bp = threadIdx.x & 15, oq = threadIdx.x >> 4;
  const int o0 = 4 * oq;
  float acc[2][4];
#pragma unroll
  for (int i = 0; i < 2; i++)
#pragma unroll
    for (int j = 0; j < 4; j++) acc[i][j] = 0.f;
  for (int k4 = 0; k4 < 72; k4++) {
    const float4 f0 = *(const float4*)&sf[bp * 300 + 4 * k4];
    const float4 f1 = *(const float4*)&sf[(bp + 16) * 300 + 4 * k4];
#pragma unroll
    for (int j = 0; j < 4; j++) {
      const float4 wr = *(const float4*)&sw1[(o0 + j) * 292 + 4 * k4];
      acc[0][j] = fmaf(f0.x, wr.x, fmaf(f0.y, wr.y, fmaf(f0.z, wr.z, fmaf(f0.w, wr.w, acc[0][j]))));
      acc[1][j] = fmaf(f1.x, wr.x, fmaf(f1.y, wr.y, fmaf(f1.z, wr.z, fmaf(f1.w, wr.w, acc[1][j]))));
    }
  }
#pragma unroll
  for (int j = 0; j < 4; j++) {
    so[bp * 65 + o0 + j] = acc[0][j];
    so[(bp + 16) * 65 + o0 + j] = acc[1][j];
  }
  __syncthreads();
  if (threadIdx.x < 64) {
    const int bb = threadIdx.x >> 1, j = threadIdx.x & 1;
    float a = sb2[j];
#pragma unroll 8
    for (int o = 0; o < 64; o++) a = fmaf(so[bb * 65 + o], sw2[j * 64 + o], a);
    out[(b0 + bb) * 144 + g * 2 + j] = a;
  }
}

extern "C" void kernel_launch(void* const* d_in, const int* in_sizes, int n_in,
                              void* d_out, int out_size, void* d_ws, size_t ws_size,
                              hipStream_t stream) {
  const float* x   = (const float*)d_in[0];
  const float* w1  = (const float*)d_in[1];
  const float* b1  = (const float*)d_in[2];
  const float* w2  = (const float*)d_in[3];
  const float* b2  = (const float*)d_in[4];
  const float* w3  = (const float*)d_in[5];
  const float* b3  = (const float*)d_in[6];
  const float* l1w = (const float*)d_in[7];
  const float* l2w = (const float*)d_in[8];
  const float* l2b = (const float*)d_in[9];
  float* out = (float*)d_out;

  float* h1 = (float*)d_ws;          // 64*576*21*21
  float* h2 = h1 + 16257024;         // 64*1152*9*9
  float* h3 = h2 + 5971968;          // 64*2304*3*3

  conv1_k<<<dim3(64 * NG), 256, 0, stream>>>(x,  w1, b1, h1);
  conv2_k<<<dim3(22 * NG), 256, 0, stream>>>(h1, w2, b2, h2);
  conv3_k<<<dim3(10 * NG), 256, 0, stream>>>(h2, w3, b3, h3);
  lin_k  <<<dim3(2 * NG),  256, 0, stream>>>(h3, l1w, l2w, l2b, out);
}

// Round 8
// 388.486 us; speedup vs baseline: 2.0945x; 2.0945x over previous
//
#include <hip/hip_runtime.h>

#define NG 72

// WIN(E,O,r,c): window element at row r, col c from de-interleaved even/odd arrays
#define WIN(E, O, r, c) (((c) & 1) ? (O)[(r)][(c) >> 1] : (E)[(r)][(c) >> 1])

// ---------------- conv1: (64,216,46,46) -> k5 g72 (3->8) -> relu -> pool2 -> (64,576,21,21)
// Two blocks per (b,g): pooled rows 0-10 / 11-20. Per block: stage only the
// needed 26/24 input rows (17KB LDS), thread = one pooled point, 8 oc in two
// sequential 4-oc halves (proven 88-VGPR live set, no spill).
__global__ __launch_bounds__(256) void conv1_k(const float* __restrict__ x,
                                               const float* __restrict__ w,
                                               const float* __restrict__ bias,
                                               float* __restrict__ out) {
  const int blk = blockIdx.x;
  const int b = blk / (NG * 2), rem = blk % (NG * 2), g = rem >> 1, yh = rem & 1;
  const int y0 = yh ? 11 : 0;          // pooled-row base
  const int ny = yh ? 10 : 11;         // pooled rows this block
  const int r0 = 2 * y0;               // first input row staged
  const int nr = yh ? 24 : 26;         // input rows staged (covers 2*(ny-1)+6)
  __shared__ float sxe[3][26][25];     // even cols (23 used), odd pitch
  __shared__ float sxo[3][26][25];     // odd cols
  __shared__ float sw[8 * 3 * 28];     // per-(oc,ic) padded 25->28, float4-aligned
  __shared__ float sb[8];
  const float* xp = x + (size_t)(b * 216 + g * 3) * 2116;
  const int nf4 = (nr * 46) >> 2;      // 299 or 276 float4 per ic (both exact)
#pragma unroll
  for (int ic = 0; ic < 3; ic++) {
    const float4* src4 = (const float4*)(xp + ic * 2116 + r0 * 46);  // 16B-aligned
    for (int i = threadIdx.x; i < nf4; i += 256) {
      const float4 v = src4[i];
#pragma unroll
      for (int j = 0; j < 4; j++) {
        const int k = 4 * i + j;
        const int r = k / 46, c = k % 46;
        if (c & 1) sxo[ic][r][c >> 1] = (&v.x)[j];
        else       sxe[ic][r][c >> 1] = (&v.x)[j];
      }
    }
  }
  const float* wp = w + (size_t)(g * 8) * 75;
  for (int i = threadIdx.x; i < 600; i += 256) {
    const int oc = i / 75, rm = i % 75, ic = rm / 25, k = rm % 25;
    sw[(oc * 3 + ic) * 28 + k] = wp[i];
  }
  if (threadIdx.x < 8) sb[threadIdx.x] = bias[g * 8 + threadIdx.x];
  __syncthreads();
  const int tid = threadIdx.x;
  if (tid < ny * 21) {
    const int yl = tid / 21, px = tid % 21;
    const int iy = 2 * yl;             // local input-row base (r0 = 2*y0 exactly)
#pragma unroll 1   // sequential halves: do NOT merge live ranges
    for (int half = 0; half < 2; half++) {
      float acc[4][4];
#pragma unroll
      for (int o = 0; o < 4; o++)
#pragma unroll
        for (int q = 0; q < 4; q++) acc[o][q] = 0.f;
#pragma unroll
      for (int ic = 0; ic < 3; ic++) {
        float we[6][3], wo[6][3];
#pragma unroll
        for (int r = 0; r < 6; r++)
#pragma unroll
          for (int j = 0; j < 3; j++) {
            we[r][j] = sxe[ic][iy + r][px + j];
            wo[r][j] = sxo[ic][iy + r][px + j];
          }
#pragma unroll
        for (int o4 = 0; o4 < 4; o4++) {
          const int oc = half * 4 + o4;
          const float4* wq = (const float4*)&sw[(oc * 3 + ic) * 28];
#pragma unroll
          for (int q = 0; q < 7; q++) {
            const float4 w4 = wq[q];   // broadcast LDS read, conflict-free
#pragma unroll
            for (int j = 0; j < 4; j++) {
              const int k = 4 * q + j;
              if (k < 25) {
                const int ky = k / 5, kx = k % 5;
                const float wv_ = (&w4.x)[j];
                acc[o4][0] = fmaf(WIN(we, wo, ky,     kx),     wv_, acc[o4][0]);
                acc[o4][1] = fmaf(WIN(we, wo, ky,     kx + 1), wv_, acc[o4][1]);
                acc[o4][2] = fmaf(WIN(we, wo, ky + 1, kx),     wv_, acc[o4][2]);
                acc[o4][3] = fmaf(WIN(we, wo, ky + 1, kx + 1), wv_, acc[o4][3]);
              }
            }
          }
        }
      }
#pragma unroll
      for (int o4 = 0; o4 < 4; o4++) {
        const int oc = half * 4 + o4;
        const float v = fmaxf(fmaxf(acc[o4][0], acc[o4][1]), fmaxf(acc[o4][2], acc[o4][3])) + sb[oc];
        out[(size_t)(b * 576 + g * 8 + oc) * 441 + (y0 + yl) * 21 + px] = fmaxf(v, 0.f);
      }
    }
  }
}

// ---------------- conv2: (64,576,21,21) -> k3 (8->16) -> relu -> pool2 -> (64,1152,9,9)
#define C2_NBB 3
__global__ __launch_bounds__(256) void conv2_k(const float* __restrict__ x,
                                               const float* __restrict__ w,
                                               const float* __restrict__ bias,
                                               float* __restrict__ out) {
  const int g = blockIdx.x % NG, b0 = (blockIdx.x / NG) * C2_NBB;
  const int nbb = min(C2_NBB, 64 - b0);
  __shared__ float sx[C2_NBB][8][21][22];
  __shared__ float sw[16 * 8 * 12];     // [oc][ic][12] (9 used), float4-aligned
  __shared__ float sb[16];
  for (int bb = 0; bb < nbb; bb++) {
    const float* xp = x + (size_t)((b0 + bb) * 576 + g * 8) * 441;
    for (int i = threadIdx.x; i < 8 * 441; i += 256) {
      const int ic = i / 441, rem = i % 441, r = rem / 21, c = rem % 21;
      sx[bb][ic][r][c] = xp[i];
    }
  }
  const float* wp = w + (size_t)(g * 16) * 72;
  for (int i = threadIdx.x; i < 16 * 72; i += 256) {
    const int oc = i / 72, rem = i % 72, ic = rem / 9, k = rem % 9;
    sw[(oc * 8 + ic) * 12 + k] = wp[i];
  }
  if (threadIdx.x < 16) sb[threadIdx.x] = bias[g * 16 + threadIdx.x];
  __syncthreads();
  for (int u = threadIdx.x; u < nbb * 81; u += 256) {
    const int bb = u / 81, p = u % 81, py = p / 9, px = p % 9;
    const int iy = 2 * py, ix = 2 * px;
#pragma unroll 1   // sequential halves
    for (int half = 0; half < 2; half++) {
      float acc[8][4];
#pragma unroll
      for (int o = 0; o < 8; o++)
#pragma unroll
        for (int q = 0; q < 4; q++) acc[o][q] = 0.f;
#pragma unroll
      for (int ic = 0; ic < 8; ic++) {
        float win[4][4];
#pragma unroll
        for (int r = 0; r < 4; r++) {
          const float2 a = *(const float2*)&sx[bb][ic][iy + r][ix];
          const float2 c2 = *(const float2*)&sx[bb][ic][iy + r][ix + 2];
          win[r][0] = a.x; win[r][1] = a.y; win[r][2] = c2.x; win[r][3] = c2.y;
        }
#pragma unroll
        for (int o8 = 0; o8 < 8; o8++) {
          const int oc = half * 8 + o8;
          const float4 wA = *(const float4*)&sw[(oc * 8 + ic) * 12];
          const float4 wB = *(const float4*)&sw[(oc * 8 + ic) * 12 + 4];
          const float  w8 = sw[(oc * 8 + ic) * 12 + 8];
          const float wv[9] = {wA.x, wA.y, wA.z, wA.w, wB.x, wB.y, wB.z, wB.w, w8};
#pragma unroll
          for (int ky = 0; ky < 3; ky++)
#pragma unroll
            for (int kx = 0; kx < 3; kx++) {
              const float wv_ = wv[ky * 3 + kx];
              acc[o8][0] = fmaf(win[ky][kx],         wv_, acc[o8][0]);
              acc[o8][1] = fmaf(win[ky][kx + 1],     wv_, acc[o8][1]);
              acc[o8][2] = fmaf(win[ky + 1][kx],     wv_, acc[o8][2]);
              acc[o8][3] = fmaf(win[ky + 1][kx + 1], wv_, acc[o8][3]);
            }
        }
      }
#pragma unroll
      for (int o8 = 0; o8 < 8; o8++) {
        const int oc = half * 8 + o8;
        const float v = fmaxf(fmaxf(acc[o8][0], acc[o8][1]), fmaxf(acc[o8][2], acc[o8][3])) + sb[oc];
        out[(size_t)((b0 + bb) * 1152 + g * 16 + oc) * 81 + p] = fmaxf(v, 0.f);
      }
    }
  }
}

// ---------------- conv3: (64,1152,9,9) -> k3 (16->32) -> relu -> pool2 -> (64,2304,3,3)
#define C3_NBB 7
__global__ __launch_bounds__(256) void conv3_k(const float* __restrict__ x,
                                               const float* __restrict__ w,
                                               const float* __restrict__ bias,
                                               float* __restrict__ out) {
  const int g = blockIdx.x % NG, b0 = (blockIdx.x / NG) * C3_NBB;
  const int nbb = min(C3_NBB, 64 - b0);
  __shared__ float sx[C3_NBB][16 * 90 + 2];
  __shared__ float sw[32 * 16 * 12];
  __shared__ float sb[32];
  for (int bb = 0; bb < nbb; bb++) {
    const float* xp = x + (size_t)((b0 + bb) * 1152 + g * 16) * 81;
    for (int i = threadIdx.x; i < 16 * 81; i += 256) {
      const int ic = i / 81, rem = i % 81, r = rem / 9, c = rem % 9;
      sx[bb][ic * 90 + r * 10 + c] = xp[i];
    }
  }
  const float* wp = w + (size_t)(g * 32) * 144;
  for (int i = threadIdx.x; i < 32 * 144; i += 256) {
    const int oc = i / 144, rem = i % 144, ic = rem / 9, k = rem % 9;
    sw[(oc * 16 + ic) * 12 + k] = wp[i];
  }
  if (threadIdx.x < 32) sb[threadIdx.x] = bias[g * 32 + threadIdx.x];
  __syncthreads();
  const int ocg = threadIdx.x >> 6;          // wave-uniform oc group
  const int lane = threadIdx.x & 63;
  const int bb = lane / 9, p = lane % 9;
  if (bb < nbb) {
    const int py = p / 3, px = p % 3, iy = 2 * py, ix = 2 * px;
    const float* sxb = &sx[bb][0];
    float acc[8][4];
#pragma unroll
    for (int o = 0; o < 8; o++)
#pragma unroll
      for (int q = 0; q < 4; q++) acc[o][q] = 0.f;
#pragma unroll
    for (int ic = 0; ic < 16; ic++) {
      float win[4][4];
#pragma unroll
      for (int r = 0; r < 4; r++) {
        const float2 a = *(const float2*)&sxb[ic * 90 + (iy + r) * 10 + ix];
        const float2 c2 = *(const float2*)&sxb[ic * 90 + (iy + r) * 10 + ix + 2];
        win[r][0] = a.x; win[r][1] = a.y; win[r][2] = c2.x; win[r][3] = c2.y;
      }
#pragma unroll
      for (int o8 = 0; o8 < 8; o8++) {
        const int oc = ocg * 8 + o8;         // wave-uniform -> broadcast reads
        const float4 wA = *(const float4*)&sw[(oc * 16 + ic) * 12];
        const float4 wB = *(const float4*)&sw[(oc * 16 + ic) * 12 + 4];
        const float  w8 = sw[(oc * 16 + ic) * 12 + 8];
        const float wv[9] = {wA.x, wA.y, wA.z, wA.w, wB.x, wB.y, wB.z, wB.w, w8};
#pragma unroll
        for (int ky = 0; ky < 3; ky++)
#pragma unroll
          for (int kx = 0; kx < 3; kx++) {
            const float wv_ = wv[ky * 3 + kx];
            acc[o8][0] = fmaf(win[ky][kx],         wv_, acc[o8][0]);
            acc[o8][1] = fmaf(win[ky][kx + 1],     wv_, acc[o8][1]);
            acc[o8][2] = fmaf(win[ky + 1][kx],     wv_, acc[o8][2]);
            acc[o8][3] = fmaf(win[ky + 1][kx + 1], wv_, acc[o8][3]);
          }
      }
    }
#pragma unroll
    for (int o8 = 0; o8 < 8; o8++) {
      const int oc = ocg * 8 + o8;
      const float v = fmaxf(fmaxf(acc[o8][0], acc[o8][1]), fmaxf(acc[o8][2], acc[o8][3])) + sb[oc];
      out[(size_t)((b0 + bb) * 2304 + g * 32 + oc) * 9 + p] = fmaxf(v, 0.f);
    }
  }
}

// ---------------- fused block-diagonal linear1 (288->64) + linear2 (64->2) + bias
__global__ __launch_bounds__(256) void lin_k(const float* __restrict__ h,
                                             const float* __restrict__ w1,
                                             const float* __restrict__ w2,
                                             const float* __restrict__ b2,
                                             float* __restrict__ out) {
  const int g = blockIdx.x % NG, b0 = (blockIdx.x / NG) * 32;
  __shared__ float sw1[64 * 292];
  __shared__ float sf[32 * 300];
  __shared__ float so[32 * 65];
  __shared__ float sw2[2 * 64];
  __shared__ float sb2[2];
  for (int i = threadIdx.x; i < 64 * 288; i += 256) {
    const int o = i / 288, k = i % 288;
    sw1[o * 292 + k] = w1[(size_t)(g * 64 + o) * 20736 + g * 288 + k];
  }
  for (int i = threadIdx.x; i < 32 * 288; i += 256) {
    const int bb = i / 288, k = i % 288;
    sf[bb * 300 + k] = h[(size_t)(b0 + bb) * 20736 + g * 288 + k];
  }
  if (threadIdx.x < 128) {
    const int j = threadIdx.x >> 6, o = threadIdx.x & 63;
    sw2[j * 64 + o] = w2[(size_t)(g * 2 + j) * 4608 + g * 64 + o];
  }
  if (threadIdx.x < 2) sb2[threadIdx.x] = b2[g * 2 + threadIdx.x];
  __syncthreads();
  const int bp = threadIdx.x & 15, oq = threadIdx.x >> 4;
  const int o0 = 4 * oq;
  float acc[2][4];
#pragma unroll
  for (int i = 0; i < 2; i++)
#pragma unroll
    for (int j = 0; j < 4; j++) acc[i][j] = 0.f;
  for (int k4 = 0; k4 < 72; k4++) {
    const float4 f0 = *(const float4*)&sf[bp * 300 + 4 * k4];
    const float4 f1 = *(const float4*)&sf[(bp + 16) * 300 + 4 * k4];
#pragma unroll
    for (int j = 0; j < 4; j++) {
      const float4 wr = *(const float4*)&sw1[(o0 + j) * 292 + 4 * k4];
      acc[0][j] = fmaf(f0.x, wr.x, fmaf(f0.y, wr.y, fmaf(f0.z, wr.z, fmaf(f0.w, wr.w, acc[0][j]))));
      acc[1][j] = fmaf(f1.x, wr.x, fmaf(f1.y, wr.y, fmaf(f1.z, wr.z, fmaf(f1.w, wr.w, acc[1][j]))));
    }
  }
#pragma unroll
  for (int j = 0; j < 4; j++) {
    so[bp * 65 + o0 + j] = acc[0][j];
    so[(bp + 16) * 65 + o0 + j] = acc[1][j];
  }
  __syncthreads();
  if (threadIdx.x < 64) {
    const int bb = threadIdx.x >> 1, j = threadIdx.x & 1;
    float a = sb2[j];
#pragma unroll 8
    for (int o = 0; o < 64; o++) a = fmaf(so[bb * 65 + o], sw2[j * 64 + o], a);
    out[(b0 + bb) * 144 + g * 2 + j] = a;
  }
}

extern "C" void kernel_launch(void* const* d_in, const int* in_sizes, int n_in,
                              void* d_out, int out_size, void* d_ws, size_t ws_size,
                              hipStream_t stream) {
  const float* x   = (const float*)d_in[0];
  const float* w1  = (const float*)d_in[1];
  const float* b1  = (const float*)d_in[2];
  const float* w2  = (const float*)d_in[3];
  const float* b2  = (const float*)d_in[4];
  const float* w3  = (const float*)d_in[5];
  const float* b3  = (const float*)d_in[6];
  const float* l1w = (const float*)d_in[7];
  const float* l2w = (const float*)d_in[8];
  const float* l2b = (const float*)d_in[9];
  float* out = (float*)d_out;

  float* h1 = (float*)d_ws;          // 64*576*21*21
  float* h2 = h1 + 16257024;         // 64*1152*9*9
  float* h3 = h2 + 5971968;          // 64*2304*3*3

  conv1_k<<<dim3(64 * NG * 2), 256, 0, stream>>>(x,  w1, b1, h1);
  conv2_k<<<dim3(22 * NG),     256, 0, stream>>>(h1, w2, b2, h2);
  conv3_k<<<dim3(10 * NG),     256, 0, stream>>>(h2, w3, b3, h3);
  lin_k  <<<dim3(2 * NG),      256, 0, stream>>>(h3, l1w, l2w, l2b, out);
}

// Round 9
// 318.078 us; speedup vs baseline: 2.5581x; 1.2214x over previous
//
#include <hip/hip_runtime.h>

#define NG 72

// WIN(E,O,r,c): window element at row r, col c from de-interleaved even/odd arrays
#define WIN(E, O, r, c) (((c) & 1) ? (O)[(r)][(c) >> 1] : (E)[(r)][(c) >> 1])

// ---------------- conv1: (64,216,46,46) -> k5 g72 (3->8) -> relu -> pool2 -> (64,576,21,21)
// Two blocks per (b,g) (pooled rows 0-10 / 11-20). Weights are block-uniform ->
// read straight from global (s_load -> SGPR operand of v_fma), no LDS staging,
// no half-split: 8 oc at once, windows read once. ~90 VGPR live set.
__global__ __launch_bounds__(256) void conv1_k(const float* __restrict__ x,
                                               const float* __restrict__ w,
                                               const float* __restrict__ bias,
                                               float* __restrict__ out) {
  const int blk = blockIdx.x;
  const int b = blk / (NG * 2), rem = blk % (NG * 2), g = rem >> 1, yh = rem & 1;
  const int y0 = yh ? 11 : 0;          // pooled-row base
  const int ny = yh ? 10 : 11;         // pooled rows this block
  const int r0 = 2 * y0;               // first input row staged
  const int nr = yh ? 24 : 26;         // input rows staged
  __shared__ float sxe[3][26][25];     // even cols (23 used), odd pitch
  __shared__ float sxo[3][26][25];     // odd cols
  const float* xp = x + (size_t)(b * 216 + g * 3) * 2116;
  const int nf4 = (nr * 46) >> 2;      // 299 or 276 float4 per ic (both exact)
#pragma unroll
  for (int ic = 0; ic < 3; ic++) {
    const float4* src4 = (const float4*)(xp + ic * 2116 + r0 * 46);  // 16B-aligned
    for (int i = threadIdx.x; i < nf4; i += 256) {
      const float4 v = src4[i];
#pragma unroll
      for (int j = 0; j < 4; j++) {
        const int k = 4 * i + j;
        const int r = k / 46, c = k % 46;
        if (c & 1) sxo[ic][r][c >> 1] = (&v.x)[j];
        else       sxe[ic][r][c >> 1] = (&v.x)[j];
      }
    }
  }
  __syncthreads();
  const float* wg = w + (size_t)(g * 8) * 75;   // uniform base -> scalar loads
  const float* bg = bias + g * 8;               // uniform
  const int tid = threadIdx.x;
  if (tid < ny * 21) {
    const int yl = tid / 21, px = tid % 21;
    const int iy = 2 * yl;
    float acc[8][4];
#pragma unroll
    for (int o = 0; o < 8; o++)
#pragma unroll
      for (int q = 0; q < 4; q++) acc[o][q] = 0.f;
#pragma unroll
    for (int ic = 0; ic < 3; ic++) {
      float we[6][3], wo[6][3];
#pragma unroll
      for (int r = 0; r < 6; r++)
#pragma unroll
        for (int j = 0; j < 3; j++) {
          we[r][j] = sxe[ic][iy + r][px + j];
          wo[r][j] = sxo[ic][iy + r][px + j];
        }
#pragma unroll
      for (int oc = 0; oc < 8; oc++) {
        const float* wq = wg + (oc * 3 + ic) * 25;   // uniform -> SGPR
#pragma unroll
        for (int ky = 0; ky < 5; ky++)
#pragma unroll
          for (int kx = 0; kx < 5; kx++) {
            const float wv_ = wq[ky * 5 + kx];
            acc[oc][0] = fmaf(WIN(we, wo, ky,     kx),     wv_, acc[oc][0]);
            acc[oc][1] = fmaf(WIN(we, wo, ky,     kx + 1), wv_, acc[oc][1]);
            acc[oc][2] = fmaf(WIN(we, wo, ky + 1, kx),     wv_, acc[oc][2]);
            acc[oc][3] = fmaf(WIN(we, wo, ky + 1, kx + 1), wv_, acc[oc][3]);
          }
      }
    }
#pragma unroll
    for (int oc = 0; oc < 8; oc++) {
      const float v = fmaxf(fmaxf(acc[oc][0], acc[oc][1]), fmaxf(acc[oc][2], acc[oc][3])) + bg[oc];
      out[(size_t)(b * 576 + g * 8 + oc) * 441 + (y0 + yl) * 21 + px] = fmaxf(v, 0.f);
    }
  }
}

// ---------------- conv2: (64,576,21,21) -> k3 (8->16) -> relu -> pool2 -> (64,1152,9,9)
// Uniform global weights (SGPR), all 16 oc in one pass (acc 64 + win 16 VGPR).
#define C2_NBB 3
__global__ __launch_bounds__(256) void conv2_k(const float* __restrict__ x,
                                               const float* __restrict__ w,
                                               const float* __restrict__ bias,
                                               float* __restrict__ out) {
  const int g = blockIdx.x % NG, b0 = (blockIdx.x / NG) * C2_NBB;
  const int nbb = min(C2_NBB, 64 - b0);
  __shared__ float sx[C2_NBB][8][21][22];
  for (int bb = 0; bb < nbb; bb++) {
    const float* xp = x + (size_t)((b0 + bb) * 576 + g * 8) * 441;
    for (int i = threadIdx.x; i < 8 * 441; i += 256) {
      const int ic = i / 441, rem = i % 441, r = rem / 21, c = rem % 21;
      sx[bb][ic][r][c] = xp[i];
    }
  }
  __syncthreads();
  const float* wg = w + (size_t)(g * 16) * 72;   // uniform
  const float* bg = bias + g * 16;               // uniform
  for (int u = threadIdx.x; u < nbb * 81; u += 256) {
    const int bb = u / 81, p = u % 81, py = p / 9, px = p % 9;
    const int iy = 2 * py, ix = 2 * px;
    float acc[16][4];
#pragma unroll
    for (int o = 0; o < 16; o++)
#pragma unroll
      for (int q = 0; q < 4; q++) acc[o][q] = 0.f;
#pragma unroll
    for (int ic = 0; ic < 8; ic++) {
      float win[4][4];
#pragma unroll
      for (int r = 0; r < 4; r++) {
        const float2 a = *(const float2*)&sx[bb][ic][iy + r][ix];
        const float2 c2 = *(const float2*)&sx[bb][ic][iy + r][ix + 2];
        win[r][0] = a.x; win[r][1] = a.y; win[r][2] = c2.x; win[r][3] = c2.y;
      }
#pragma unroll
      for (int oc = 0; oc < 16; oc++) {
        const float* wq = wg + (oc * 8 + ic) * 9;  // uniform -> SGPR
#pragma unroll
        for (int ky = 0; ky < 3; ky++)
#pragma unroll
          for (int kx = 0; kx < 3; kx++) {
            const float wv_ = wq[ky * 3 + kx];
            acc[oc][0] = fmaf(win[ky][kx],         wv_, acc[oc][0]);
            acc[oc][1] = fmaf(win[ky][kx + 1],     wv_, acc[oc][1]);
            acc[oc][2] = fmaf(win[ky + 1][kx],     wv_, acc[oc][2]);
            acc[oc][3] = fmaf(win[ky + 1][kx + 1], wv_, acc[oc][3]);
          }
      }
    }
#pragma unroll
    for (int oc = 0; oc < 16; oc++) {
      const float v = fmaxf(fmaxf(acc[oc][0], acc[oc][1]), fmaxf(acc[oc][2], acc[oc][3])) + bg[oc];
      out[(size_t)((b0 + bb) * 1152 + g * 16 + oc) * 81 + p] = fmaxf(v, 0.f);
    }
  }
}

// ---------------- conv3: (64,1152,9,9) -> k3 (16->32) -> relu -> pool2 -> (64,2304,3,3)
// ocg forced scalar via readfirstlane -> weight addresses uniform -> s_load.
#define C3_NBB 7
__global__ __launch_bounds__(256) void conv3_k(const float* __restrict__ x,
                                               const float* __restrict__ w,
                                               const float* __restrict__ bias,
                                               float* __restrict__ out) {
  const int g = blockIdx.x % NG, b0 = (blockIdx.x / NG) * C3_NBB;
  const int nbb = min(C3_NBB, 64 - b0);
  __shared__ float sx[C3_NBB][16 * 90 + 2];
  for (int bb = 0; bb < nbb; bb++) {
    const float* xp = x + (size_t)((b0 + bb) * 1152 + g * 16) * 81;
    for (int i = threadIdx.x; i < 16 * 81; i += 256) {
      const int ic = i / 81, rem = i % 81, r = rem / 9, c = rem % 9;
      sx[bb][ic * 90 + r * 10 + c] = xp[i];
    }
  }
  __syncthreads();
  const int ocg = __builtin_amdgcn_readfirstlane(threadIdx.x >> 6);  // wave-uniform, scalar
  const float* wg = w + ((size_t)(g * 32 + ocg * 8) * 16) * 9;       // uniform
  const float* bg = bias + g * 32 + ocg * 8;                         // uniform
  const int lane = threadIdx.x & 63;
  const int bb = lane / 9, p = lane % 9;
  if (bb < nbb) {
    const int py = p / 3, px = p % 3, iy = 2 * py, ix = 2 * px;
    const float* sxb = &sx[bb][0];
    float acc[8][4];
#pragma unroll
    for (int o = 0; o < 8; o++)
#pragma unroll
      for (int q = 0; q < 4; q++) acc[o][q] = 0.f;
#pragma unroll
    for (int ic = 0; ic < 16; ic++) {
      float win[4][4];
#pragma unroll
      for (int r = 0; r < 4; r++) {
        const float2 a = *(const float2*)&sxb[ic * 90 + (iy + r) * 10 + ix];
        const float2 c2 = *(const float2*)&sxb[ic * 90 + (iy + r) * 10 + ix + 2];
        win[r][0] = a.x; win[r][1] = a.y; win[r][2] = c2.x; win[r][3] = c2.y;
      }
#pragma unroll
      for (int o8 = 0; o8 < 8; o8++) {
        const float* wq = wg + (o8 * 16 + ic) * 9;   // uniform -> SGPR
#pragma unroll
        for (int ky = 0; ky < 3; ky++)
#pragma unroll
          for (int kx = 0; kx < 3; kx++) {
            const float wv_ = wq[ky * 3 + kx];
            acc[o8][0] = fmaf(win[ky][kx],         wv_, acc[o8][0]);
            acc[o8][1] = fmaf(win[ky][kx + 1],     wv_, acc[o8][1]);
            acc[o8][2] = fmaf(win[ky + 1][kx],     wv_, acc[o8][2]);
            acc[o8][3] = fmaf(win[ky + 1][kx + 1], wv_, acc[o8][3]);
          }
      }
    }
#pragma unroll
    for (int o8 = 0; o8 < 8; o8++) {
      const float v = fmaxf(fmaxf(acc[o8][0], acc[o8][1]), fmaxf(acc[o8][2], acc[o8][3])) + bg[o8];
      out[(size_t)((b0 + bb) * 2304 + g * 32 + ocg * 8 + o8) * 9 + p] = fmaxf(v, 0.f);
    }
  }
}

// ---------------- fused block-diagonal linear1 (288->64) + linear2 (64->2) + bias
__global__ __launch_bounds__(256) void lin_k(const float* __restrict__ h,
                                             const float* __restrict__ w1,
                                             const float* __restrict__ w2,
                                             const float* __restrict__ b2,
                                             float* __restrict__ out) {
  const int g = blockIdx.x % NG, b0 = (blockIdx.x / NG) * 32;
  __shared__ float sw1[64 * 292];
  __shared__ float sf[32 * 300];
  __shared__ float so[32 * 65];
  __shared__ float sw2[2 * 64];
  __shared__ float sb2[2];
  for (int i = threadIdx.x; i < 64 * 288; i += 256) {
    const int o = i / 288, k = i % 288;
    sw1[o * 292 + k] = w1[(size_t)(g * 64 + o) * 20736 + g * 288 + k];
  }
  for (int i = threadIdx.x; i < 32 * 288; i += 256) {
    const int bb = i / 288, k = i % 288;
    sf[bb * 300 + k] = h[(size_t)(b0 + bb) * 20736 + g * 288 + k];
  }
  if (threadIdx.x < 128) {
    const int j = threadIdx.x >> 6, o = threadIdx.x & 63;
    sw2[j * 64 + o] = w2[(size_t)(g * 2 + j) * 4608 + g * 64 + o];
  }
  if (threadIdx.x < 2) sb2[threadIdx.x] = b2[g * 2 + threadIdx.x];
  __syncthreads();
  const int bp = threadIdx.x & 15, oq = threadIdx.x >> 4;
  const int o0 = 4 * oq;
  float acc[2][4];
#pragma unroll
  for (int i = 0; i < 2; i++)
#pragma unroll
    for (int j = 0; j < 4; j++) acc[i][j] = 0.f;
  for (int k4 = 0; k4 < 72; k4++) {
    const float4 f0 = *(const float4*)&sf[bp * 300 + 4 * k4];
    const float4 f1 = *(const float4*)&sf[(bp + 16) * 300 + 4 * k4];
#pragma unroll
    for (int j = 0; j < 4; j++) {
      const float4 wr = *(const float4*)&sw1[(o0 + j) * 292 + 4 * k4];
      acc[0][j] = fmaf(f0.x, wr.x, fmaf(f0.y, wr.y, fmaf(f0.z, wr.z, fmaf(f0.w, wr.w, acc[0][j]))));
      acc[1][j] = fmaf(f1.x, wr.x, fmaf(f1.y, wr.y, fmaf(f1.z, wr.z, fmaf(f1.w, wr.w, acc[1][j]))));
    }
  }
#pragma unroll
  for (int j = 0; j < 4; j++) {
    so[bp * 65 + o0 + j] = acc[0][j];
    so[(bp + 16) * 65 + o0 + j] = acc[1][j];
  }
  __syncthreads();
  if (threadIdx.x < 64) {
    const int bb = threadIdx.x >> 1, j = threadIdx.x & 1;
    float a = sb2[j];
#pragma unroll 8
    for (int o = 0; o < 64; o++) a = fmaf(so[bb * 65 + o], sw2[j * 64 + o], a);
    out[(b0 + bb) * 144 + g * 2 + j] = a;
  }
}

extern "C" void kernel_launch(void* const* d_in, const int* in_sizes, int n_in,
                              void* d_out, int out_size, void* d_ws, size_t ws_size,
                              hipStream_t stream) {
  const float* x   = (const float*)d_in[0];
  const float* w1  = (const float*)d_in[1];
  const float* b1  = (const float*)d_in[2];
  const float* w2  = (const float*)d_in[3];
  const float* b2  = (const float*)d_in[4];
  const float* w3  = (const float*)d_in[5];
  const float* b3  = (const float*)d_in[6];
  const float* l1w = (const float*)d_in[7];
  const float* l2w = (const float*)d_in[8];
  const float* l2b = (const float*)d_in[9];
  float* out = (float*)d_out;

  float* h1 = (float*)d_ws;          // 64*576*21*21
  float* h2 = h1 + 16257024;         // 64*1152*9*9
  float* h3 = h2 + 5971968;          // 64*2304*3*3

  conv1_k<<<dim3(64 * NG * 2), 256, 0, stream>>>(x,  w1, b1, h1);
  conv2_k<<<dim3(22 * NG),     256, 0, stream>>>(h1, w2, b2, h2);
  conv3_k<<<dim3(10 * NG),     256, 0, stream>>>(h2, w3, b3, h3);
  lin_k  <<<dim3(2 * NG),      256, 0, stream>>>(h3, l1w, l2w, l2b, out);
}